// Round 1
// baseline (1427.035 us; speedup 1.0000x reference)
//
#include <hip/hip_runtime.h>
#include <hip/hip_bf16.h>

#define BB 64
#define PP 100
#define NN 1000
#define EE 512
#define HH 8
#define KDD 64
#define MM 10
#define ROWS (BB*PP)          // 6400
#define K1K 1026              // 2E+2
#define INVSQE 0.044194173824159216f  // 1/sqrt(512)
#define CLIPV 10.0f

union F4 { float4 v; float f[4]; };

// ---------------------------------------------------------------- K0: row max of cur_dist
__global__ __launch_bounds__(256) void k_rowmax(const float* __restrict__ cd,
                                                float* __restrict__ rmax) {
  int row = blockIdx.x * 4 + (threadIdx.x >> 6);
  int lane = threadIdx.x & 63;
  const float* src = cd + (size_t)row * NN;
  float m = -1e30f;
  for (int i = lane; i < NN; i += 64) m = fmaxf(m, src[i]);
  #pragma unroll
  for (int off = 32; off; off >>= 1) m = fmaxf(m, __shfl_xor(m, off));
  if (lane == 0) rmax[row] = m;
}

// ---------------------------------------------------------------- K1: q = q_first + heads(X @ Wq^T) + heads(info @ dis_emb^T)
// X[row][0:512]=eln, [512:1024]=ela, [1024]=frac, [1025]=lc.  out layout [row][512] (o = h*64+kd)
__global__ __launch_bounds__(256) void k_qgemm(
    const float* __restrict__ eln, const float* __restrict__ ela,
    const float* __restrict__ lengths, const float* __restrict__ max_dis,
    const float* __restrict__ remain, const float* __restrict__ q_first,
    const float* __restrict__ Wq, const float* __restrict__ dis_emb,
    const int* __restrict__ depot, const int* __restrict__ route_cnt,
    const int* __restrict__ left_city, const int* __restrict__ city_num,
    float* __restrict__ qout) {
  __shared__ float Xs[64][36];
  __shared__ float Ws[64][36];
  __shared__ float info_s[64][4];
  __shared__ float fl_s[64][2];
  const int t = threadIdx.x;
  const int rowBase = blockIdx.y * 64, colBase = blockIdx.x * 64;
  if (t < 64) {
    int row = rowBase + t;
    int b = row / PP;
    int rc = route_cnt[row];
    int rn = depot[b] - 1;
    info_s[t][0] = lengths[row * MM + rc];
    info_s[t][1] = lengths[row * MM + rn];
    info_s[t][2] = max_dis[row];
    info_s[t][3] = remain[row];
    fl_s[t][0] = 1.0f - (float)(rc + 1) / (float)(rn + 1);
    fl_s[t][1] = (float)left_city[row] / (float)city_num[0];
  }
  __syncthreads();
  float acc[4][4];
  #pragma unroll
  for (int i = 0; i < 4; ++i)
    #pragma unroll
    for (int j = 0; j < 4; ++j) acc[i][j] = 0.f;
  const int tx = t & 15, ty = t >> 4;
  for (int kt = 0; kt < 33; ++kt) {
    const int k0 = kt * 32;
    #pragma unroll
    for (int i = 0; i < 8; ++i) {
      int e = i * 256 + t;
      int r = e >> 5, c = e & 31;
      int j = k0 + c;
      int row = rowBase + r;
      float xv;
      if (j < 512)       xv = eln[(size_t)row * 512 + j];
      else if (j < 1024) xv = ela[(size_t)row * 512 + j - 512];
      else if (j == 1024) xv = fl_s[r][0];
      else if (j == 1025) xv = fl_s[r][1];
      else xv = 0.f;
      Xs[r][c] = xv;
      Ws[r][c] = (j < K1K) ? Wq[(size_t)(colBase + r) * K1K + j] : 0.f;
    }
    __syncthreads();
    #pragma unroll
    for (int kc = 0; kc < 32; kc += 4) {
      F4 xv[4], wv[4];
      #pragma unroll
      for (int i = 0; i < 4; ++i) xv[i].v = *(const float4*)&Xs[ty + 16 * i][kc];
      #pragma unroll
      for (int j = 0; j < 4; ++j) wv[j].v = *(const float4*)&Ws[tx + 16 * j][kc];
      #pragma unroll
      for (int c = 0; c < 4; ++c)
        #pragma unroll
        for (int i = 0; i < 4; ++i)
          #pragma unroll
          for (int j = 0; j < 4; ++j)
            acc[i][j] += xv[i].f[c] * wv[j].f[c];
    }
    __syncthreads();
  }
  #pragma unroll
  for (int i = 0; i < 4; ++i) {
    int r = ty + 16 * i;
    int row = rowBase + r;
    int b = row / PP, p = row % PP;
    F4 inf; inf.v = *(const float4*)&info_s[r][0];
    #pragma unroll
    for (int j = 0; j < 4; ++j) {
      int o = colBase + tx + 16 * j;
      F4 de; de.v = *(const float4*)&dis_emb[(size_t)o * 4];
      float v = acc[i][j]
              + inf.f[0] * de.f[0] + inf.f[1] * de.f[1]
              + inf.f[2] * de.f[2] + inf.f[3] * de.f[3]
              + q_first[(((size_t)b * HH + (o >> 6)) * PP + p) * KDD + (o & 63)];
      qout[(size_t)row * 512 + o] = v;
    }
  }
}

// ---------------------------------------------------------------- K2: masked MHA, one block per (b,h), online softmax
__global__ __launch_bounds__(256) void k_attn(
    const float* __restrict__ qin, const float* __restrict__ kk,
    const float* __restrict__ vv, const float* __restrict__ mask,
    float* __restrict__ attn_out) {
  __shared__ float q_s[104][68];
  __shared__ float k_s[32][68];
  __shared__ float v_s[32][68];
  __shared__ float S[104][33];
  __shared__ float r_s[104], l_s[104];
  const int t = threadIdx.x;
  const int bh = blockIdx.x, b = bh >> 3, h = bh & 7;

  for (int idx = t; idx < 104 * 16; idx += 256) {
    int qi = idx >> 4, c4 = (idx & 15) * 4;
    float4 qv = make_float4(0.f, 0.f, 0.f, 0.f);
    if (qi < PP) qv = *(const float4*)&qin[((size_t)(b * PP + qi)) * 512 + h * 64 + c4];
    qv.x *= 0.125f; qv.y *= 0.125f; qv.z *= 0.125f; qv.w *= 0.125f;
    *(float4*)&q_s[qi][c4] = qv;
  }
  if (t < 104) { r_s[t] = 1.f; l_s[t] = 0.f; }
  float mrun = -1e30f, lrun = 0.f;
  float acc[4][8];
  #pragma unroll
  for (int i = 0; i < 4; ++i)
    #pragma unroll
    for (int j = 0; j < 8; ++j) acc[i][j] = 0.f;
  const int qiA = t >> 3, ngA = t & 7;
  const int qiB = t >> 3, dgB = (t & 7) * 8;
  int rA[4]; rA[0] = qiA; rA[1] = qiA + 32; rA[2] = qiA + 64; rA[3] = (qiA + 96 < 104) ? qiA + 96 : 103;
  int rB[4]; rB[0] = qiB; rB[1] = qiB + 32; rB[2] = qiB + 64; rB[3] = (qiB + 96 < 104) ? qiB + 96 : 103;
  __syncthreads();

  for (int ch = 0; ch < 32; ++ch) {
    const int n0 = ch * 32;
    for (int idx = t; idx < 32 * 16; idx += 256) {
      int r = idx >> 4, c4 = (idx & 15) * 4;
      int n = n0 + r;
      float4 kv = make_float4(0.f, 0.f, 0.f, 0.f), v4 = kv;
      if (n < NN) {
        size_t base = ((size_t)bh * NN + n) * 64 + c4;
        kv = *(const float4*)&kk[base];
        v4 = *(const float4*)&vv[base];
      }
      *(float4*)&k_s[r][c4] = kv;
      *(float4*)&v_s[r][c4] = v4;
    }
    __syncthreads();
    // phase A: scores
    {
      float sacc[4][4];
      #pragma unroll
      for (int i = 0; i < 4; ++i)
        #pragma unroll
        for (int j = 0; j < 4; ++j) sacc[i][j] = 0.f;
      #pragma unroll
      for (int d = 0; d < 64; d += 4) {
        F4 qv[4], kv[4];
        #pragma unroll
        for (int i = 0; i < 4; ++i) qv[i].v = *(const float4*)&q_s[rA[i]][d];
        #pragma unroll
        for (int j = 0; j < 4; ++j) kv[j].v = *(const float4*)&k_s[ngA + 8 * j][d];
        #pragma unroll
        for (int c = 0; c < 4; ++c)
          #pragma unroll
          for (int i = 0; i < 4; ++i)
            #pragma unroll
            for (int j = 0; j < 4; ++j)
              sacc[i][j] += qv[i].f[c] * kv[j].f[c];
      }
      #pragma unroll
      for (int i = 0; i < 4; ++i) {
        int qi = qiA + 32 * i;
        if (qi < 104) {
          #pragma unroll
          for (int j = 0; j < 4; ++j) S[qi][ngA + 8 * j] = sacc[i][j];
        }
      }
    }
    __syncthreads();
    // softmax update (one thread per query row)
    if (t < 104) {
      if (t < PP) {
        const int qi = t;
        const float* mrow = &mask[((size_t)(b * PP + qi)) * NN + n0];
        float sv[32];
        float cm = -1e30f;
        #pragma unroll
        for (int n = 0; n < 32; ++n) {
          float s = -1e30f;
          if (n0 + n < NN) s = S[qi][n] + mrow[n];
          sv[n] = s;
          cm = fmaxf(cm, s);
        }
        float newm = fmaxf(mrun, cm);
        float r = __expf(mrun - newm);
        float sum = 0.f;
        #pragma unroll
        for (int n = 0; n < 32; ++n) {
          float e = __expf(sv[n] - newm);
          S[qi][n] = e;
          sum += e;
        }
        mrun = newm;
        lrun = lrun * r + sum;
        r_s[qi] = r;
        l_s[qi] = lrun;
      } else {
        r_s[t] = 1.f;
      }
    }
    __syncthreads();
    // phase B: out accumulation
    {
      float rr0 = r_s[rB[0]], rr1 = r_s[rB[1]], rr2 = r_s[rB[2]], rr3 = r_s[rB[3]];
      #pragma unroll
      for (int j = 0; j < 8; ++j) {
        acc[0][j] *= rr0; acc[1][j] *= rr1; acc[2][j] *= rr2; acc[3][j] *= rr3;
      }
      #pragma unroll
      for (int n = 0; n < 32; ++n) {
        F4 va, vb;
        va.v = *(const float4*)&v_s[n][dgB];
        vb.v = *(const float4*)&v_s[n][dgB + 4];
        float w0 = S[rB[0]][n], w1 = S[rB[1]][n], w2 = S[rB[2]][n], w3 = S[rB[3]][n];
        #pragma unroll
        for (int c = 0; c < 4; ++c) {
          acc[0][c] += w0 * va.f[c]; acc[0][c + 4] += w0 * vb.f[c];
          acc[1][c] += w1 * va.f[c]; acc[1][c + 4] += w1 * vb.f[c];
          acc[2][c] += w2 * va.f[c]; acc[2][c + 4] += w2 * vb.f[c];
          acc[3][c] += w3 * va.f[c]; acc[3][c + 4] += w3 * vb.f[c];
        }
      }
    }
    __syncthreads();
  }
  // epilogue
  #pragma unroll
  for (int i = 0; i < 4; ++i) {
    int qi = qiB + 32 * i;
    if (qi < PP) {
      float inv = 1.0f / l_s[qi];
      size_t base = ((size_t)(b * PP + qi)) * 512 + h * 64 + dgB;
      float4 o1 = make_float4(acc[i][0] * inv, acc[i][1] * inv, acc[i][2] * inv, acc[i][3] * inv);
      float4 o2 = make_float4(acc[i][4] * inv, acc[i][5] * inv, acc[i][6] * inv, acc[i][7] * inv);
      *(float4*)&attn_out[base] = o1;
      *(float4*)&attn_out[base + 4] = o2;
    }
  }
}

// ---------------------------------------------------------------- K3: mh = attn_out @ mh_w^T + mh_b
__global__ __launch_bounds__(256) void k_mhgemm(
    const float* __restrict__ A, const float* __restrict__ W,
    const float* __restrict__ bias, float* __restrict__ out) {
  __shared__ float Xs[64][36];
  __shared__ float Ws[64][36];
  const int t = threadIdx.x;
  const int rowBase = blockIdx.y * 64, colBase = blockIdx.x * 64;
  const int tx = t & 15, ty = t >> 4;
  float acc[4][4];
  #pragma unroll
  for (int i = 0; i < 4; ++i)
    #pragma unroll
    for (int j = 0; j < 4; ++j) acc[i][j] = 0.f;
  for (int kt = 0; kt < 16; ++kt) {
    const int k0 = kt * 32;
    #pragma unroll
    for (int i = 0; i < 8; ++i) {
      int e = i * 256 + t;
      int r = e >> 5, c = e & 31;
      Xs[r][c] = A[(size_t)(rowBase + r) * 512 + k0 + c];
      Ws[r][c] = W[(size_t)(colBase + r) * 512 + k0 + c];
    }
    __syncthreads();
    #pragma unroll
    for (int kc = 0; kc < 32; kc += 4) {
      F4 xv[4], wv[4];
      #pragma unroll
      for (int i = 0; i < 4; ++i) xv[i].v = *(const float4*)&Xs[ty + 16 * i][kc];
      #pragma unroll
      for (int j = 0; j < 4; ++j) wv[j].v = *(const float4*)&Ws[tx + 16 * j][kc];
      #pragma unroll
      for (int c = 0; c < 4; ++c)
        #pragma unroll
        for (int i = 0; i < 4; ++i)
          #pragma unroll
          for (int j = 0; j < 4; ++j)
            acc[i][j] += xv[i].f[c] * wv[j].f[c];
    }
    __syncthreads();
  }
  #pragma unroll
  for (int i = 0; i < 4; ++i) {
    int row = rowBase + ty + 16 * i;
    #pragma unroll
    for (int j = 0; j < 4; ++j) {
      int o = colBase + tx + 16 * j;
      out[(size_t)row * 512 + o] = acc[i][j] + bias[o];
    }
  }
}

// ---------------------------------------------------------------- K4a: score2 = mh @ shk, then 10*tanh(s/sqrtE - a*cd/cdmax) + mask
__global__ __launch_bounds__(256) void k_final_score(
    const float* __restrict__ mh, const float* __restrict__ shk,
    const float* __restrict__ cur_dist, const float* __restrict__ rmax,
    const float* __restrict__ mask, const float* __restrict__ dist_alpha,
    float* __restrict__ sc_out) {
  __shared__ float mh_s[16][36];
  __shared__ float shk_s[32][260];
  const int t = threadIdx.x;
  const int b = blockIdx.z, p0 = blockIdx.y * 16, n0 = blockIdx.x * 256;
  const int pg = t >> 6, ng = t & 63;
  float acc[4][4];
  #pragma unroll
  for (int i = 0; i < 4; ++i)
    #pragma unroll
    for (int j = 0; j < 4; ++j) acc[i][j] = 0.f;
  for (int kt = 0; kt < 16; ++kt) {
    const int k0 = kt * 32;
    if (t < 128) {
      int r = t >> 3, c4 = (t & 7) * 4;
      float4 mv = make_float4(0.f, 0.f, 0.f, 0.f);
      if (p0 + r < PP) mv = *(const float4*)&mh[((size_t)(b * PP + p0 + r)) * 512 + k0 + c4];
      *(float4*)&mh_s[r][c4] = mv;
    }
    #pragma unroll
    for (int i = 0; i < 8; ++i) {
      int idx = i * 256 + t;
      int e = idx >> 6, n4 = (idx & 63) * 4;
      int n = n0 + n4;
      const float* src = &shk[((size_t)(b * 512 + k0 + e)) * NN + n];
      float4 sv = make_float4(0.f, 0.f, 0.f, 0.f);
      if (n + 3 < NN) sv = *(const float4*)src;
      else if (n < NN) {
        sv.x = src[0];
        if (n + 1 < NN) sv.y = src[1];
        if (n + 2 < NN) sv.z = src[2];
      }
      *(float4*)&shk_s[e][n4] = sv;
    }
    __syncthreads();
    #pragma unroll
    for (int k = 0; k < 32; k += 4) {
      F4 a0, a1, a2, a3;
      a0.v = *(const float4*)&mh_s[pg * 4 + 0][k];
      a1.v = *(const float4*)&mh_s[pg * 4 + 1][k];
      a2.v = *(const float4*)&mh_s[pg * 4 + 2][k];
      a3.v = *(const float4*)&mh_s[pg * 4 + 3][k];
      #pragma unroll
      for (int kk = 0; kk < 4; ++kk) {
        F4 bv; bv.v = *(const float4*)&shk_s[k + kk][ng * 4];
        #pragma unroll
        for (int c = 0; c < 4; ++c) {
          acc[0][c] += a0.f[kk] * bv.f[c];
          acc[1][c] += a1.f[kk] * bv.f[c];
          acc[2][c] += a2.f[kk] * bv.f[c];
          acc[3][c] += a3.f[kk] * bv.f[c];
        }
      }
    }
    __syncthreads();
  }
  const float alpha = dist_alpha[0];
  #pragma unroll
  for (int i = 0; i < 4; ++i) {
    int p = p0 + pg * 4 + i;
    if (p >= PP) continue;
    size_t rb = (size_t)(b * PP + p) * NN;
    float rmx = rmax[b * PP + p];
    int n = n0 + ng * 4;
    if (n >= NN) continue;
    if (n + 3 < NN) {
      F4 cd, mk, o;
      cd.v = *(const float4*)&cur_dist[rb + n];
      mk.v = *(const float4*)&mask[rb + n];
      #pragma unroll
      for (int j = 0; j < 4; ++j)
        o.f[j] = CLIPV * tanhf(acc[i][j] * INVSQE - alpha * cd.f[j] / rmx) + mk.f[j];
      *(float4*)&sc_out[rb + n] = o.v;
    } else {
      #pragma unroll
      for (int j = 0; j < 4; ++j) {
        if (n + j < NN) {
          float cd = cur_dist[rb + n + j];
          float mk = mask[rb + n + j];
          sc_out[rb + n + j] = CLIPV * tanhf(acc[i][j] * INVSQE - alpha * cd / rmx) + mk;
        }
      }
    }
  }
}

// ---------------------------------------------------------------- K4b: row softmax over N
__global__ __launch_bounds__(256) void k_softmax(const float* __restrict__ sc,
                                                 float* __restrict__ out) {
  __shared__ float redm[4];
  __shared__ float redsum[4];
  const int row = blockIdx.x;
  const int t = threadIdx.x;
  const float* src = sc + (size_t)row * NN;
  float v0[4];
  float m = -1e30f;
  #pragma unroll
  for (int i = 0; i < 4; ++i) {
    int n = i * 256 + t;
    v0[i] = (n < NN) ? src[n] : -1e30f;
    m = fmaxf(m, v0[i]);
  }
  #pragma unroll
  for (int off = 32; off; off >>= 1) m = fmaxf(m, __shfl_xor(m, off));
  int wid = t >> 6, lane = t & 63;
  if (lane == 0) redm[wid] = m;
  __syncthreads();
  m = fmaxf(fmaxf(redm[0], redm[1]), fmaxf(redm[2], redm[3]));
  float e[4];
  float s = 0.f;
  #pragma unroll
  for (int i = 0; i < 4; ++i) {
    int n = i * 256 + t;
    e[i] = (n < NN) ? __expf(v0[i] - m) : 0.f;
    s += e[i];
  }
  #pragma unroll
  for (int off = 32; off; off >>= 1) s += __shfl_xor(s, off);
  if (lane == 0) redsum[wid] = s;
  __syncthreads();
  s = redsum[0] + redsum[1] + redsum[2] + redsum[3];
  float inv = 1.0f / s;
  #pragma unroll
  for (int i = 0; i < 4; ++i) {
    int n = i * 256 + t;
    if (n < NN) out[(size_t)row * NN + n] = e[i] * inv;
  }
}

// ----------------------------------------------------------------
extern "C" void kernel_launch(void* const* d_in, const int* in_sizes, int n_in,
                              void* d_out, int out_size, void* d_ws, size_t ws_size,
                              hipStream_t stream) {
  const float* eln       = (const float*)d_in[0];
  const float* ela       = (const float*)d_in[1];
  const float* cur_dist  = (const float*)d_in[2];
  const float* ninf      = (const float*)d_in[3];
  const float* lengths   = (const float*)d_in[4];
  const float* max_dis   = (const float*)d_in[5];
  const float* remain    = (const float*)d_in[6];
  const float* q_first   = (const float*)d_in[7];
  const float* kten      = (const float*)d_in[8];
  const float* vten      = (const float*)d_in[9];
  const float* shk       = (const float*)d_in[10];
  const float* Wq        = (const float*)d_in[11];
  const float* dis_emb   = (const float*)d_in[12];
  const float* mh_w      = (const float*)d_in[13];
  const float* mh_b      = (const float*)d_in[14];
  const float* dalpha    = (const float*)d_in[15];
  const int*   depot     = (const int*)d_in[16];
  const int*   route_cnt = (const int*)d_in[17];
  const int*   left_city = (const int*)d_in[18];
  const int*   city_num  = (const int*)d_in[19];
  float* out = (float*)d_out;

  float* ws      = (float*)d_ws;
  float* q_ws    = ws;                                   // 6400*512
  float* attn_ws = q_ws + (size_t)ROWS * 512;            // 6400*512
  float* mh_ws   = attn_ws + (size_t)ROWS * 512;         // 6400*512
  float* sc_ws   = mh_ws + (size_t)ROWS * 512;           // 6400*1000
  float* rmax_ws = sc_ws + (size_t)ROWS * NN;            // 6400

  k_rowmax<<<ROWS / 4, 256, 0, stream>>>(cur_dist, rmax_ws);
  k_qgemm<<<dim3(8, 100), 256, 0, stream>>>(eln, ela, lengths, max_dis, remain,
                                            q_first, Wq, dis_emb, depot, route_cnt,
                                            left_city, city_num, q_ws);
  k_attn<<<BB * HH, 256, 0, stream>>>(q_ws, kten, vten, ninf, attn_ws);
  k_mhgemm<<<dim3(8, 100), 256, 0, stream>>>(attn_ws, mh_w, mh_b, mh_ws);
  k_final_score<<<dim3(4, 7, 64), 256, 0, stream>>>(mh_ws, shk, cur_dist, rmax_ws,
                                                    ninf, dalpha, sc_ws);
  k_softmax<<<ROWS, 256, 0, stream>>>(sc_ws, out);
}